// Round 16
// baseline (889.712 us; speedup 1.0000x reference)
//
#include <hip/hip_runtime.h>

#define BATCH 4
#define SLEN 4096
#define DDIM 512
#define GDIM 64
#define NORIG 4096
#define WMAX 15            // d = 1..15 (window_size 16)
#define RSEL 1024
#define KEEP (SLEN - RSEL) // 3072
#define NTOK (BATCH * SLEN)
#define PEEL_ROUNDS 256
#define LDSL 16            // LDS-resident list entries per token (global fallback past this)

typedef float __attribute__((ext_vector_type(4))) f32x4;

// ---- workspace layout (bytes) ----
// gn region [0, 8.4MB) is dead after k_sims -> reuse for peel scratch.
#define OFF_TCODE ((size_t)0)            // u16    [B][2048]    = 16,384   (reuses gn)
#define OFF_TCNT  ((size_t)16384)        // int    [B]          = 16       (reuses gn)
#define OFF_LISTS ((size_t)32768)        // i8     [B][S][32]   = 524,288  (reuses gn)
#define OFF_GN    ((size_t)0)            // double [B][S][G]    = 8,388,608
#define OFF_SIMST ((size_t)8388608)      // double [B][S][16]   = 2,097,152  (slot d=1..15)
#define OFF_NORMS ((size_t)10485760)     // float  [B][S]       = 65,536
#define OFF_KT    ((size_t)10584064)     // int    [B][KEEP]    = 49,152
#define OFF_PJR   ((size_t)10633216)     // int    [B][KEEP]
#define OFF_WIR   ((size_t)10682368)     // float  [B][KEEP]
#define OFF_WJR   ((size_t)10731520)     // float  [B][KEEP]
#define WS_NEEDED ((size_t)10780672)

// ---- output layout (f32 elements) ----
#define OUTX_OFF 0
#define OUTS_OFF 6291456          // 4*3072*512
#define OUTP_OFF 56623104         // + 4*3072*4096

// K1: g = x@W in f64, norms, gn = g/max(norm,1e-12).
__global__ __launch_bounds__(256) void k_proj(const float* __restrict__ x,
                                              const float* __restrict__ Wm,
                                              double* __restrict__ gn,
                                              float* __restrict__ norms) {
  __shared__ float xs[16 * DDIM];
  int base = blockIdx.x * 16;
  const float4* src = (const float4*)(x + (size_t)base * DDIM);
  float4* dstv = (float4*)xs;
  for (int idx = threadIdx.x; idx < 16 * DDIM / 4; idx += 256) dstv[idx] = src[idx];
  __syncthreads();
  int lane = threadIdx.x & 63;
  int wv = threadIdx.x >> 6;
  double acc0 = 0, acc1 = 0, acc2 = 0, acc3 = 0;
  const float* xw = xs + wv * 4 * DDIM;
  for (int d = 0; d < DDIM; ++d) {
    double wval = (double)Wm[d * GDIM + lane];
    acc0 += (double)xw[d] * wval;
    acc1 += (double)xw[DDIM + d] * wval;
    acc2 += (double)xw[2 * DDIM + d] * wval;
    acc3 += (double)xw[3 * DDIM + d] * wval;
  }
  double accs[4] = {acc0, acc1, acc2, acc3};
  for (int k = 0; k < 4; ++k) {
    double a = accs[k];
    double ss = a * a;
    for (int o = 32; o >= 1; o >>= 1) ss += __shfl_xor(ss, o, 64);
    double nrm = sqrt(ss);
    int tok = base + wv * 4 + k;
    if (lane == 0) norms[tok] = (float)nrm;
    double denom = nrm > 1e-12 ? nrm : 1e-12;
    gn[(size_t)tok * GDIM + lane] = a / denom;
  }
}

// K2: sims for pairs (i, i+d), token-major: simsT[(b*S+i)*16 + d].
__global__ __launch_bounds__(256) void k_sims(const double* __restrict__ gn,
                                              double* __restrict__ simsT) {
  int blk = blockIdx.x;
  int b = blk >> 6;
  int t0 = (blk & 63) * 64;
  int nrows = min(64 + WMAX, SLEN - t0);
  __shared__ double gs[(64 + WMAX) * GDIM];
  const double* src = gn + ((size_t)b * SLEN + t0) * GDIM;
  for (int idx = threadIdx.x; idx < nrows * GDIM; idx += 256) gs[idx] = src[idx];
  __syncthreads();
  int lane = threadIdx.x & 63, wv = threadIdx.x >> 6;
  for (int s = wv; s < 64 * WMAX; s += 4) {
    int il = s & 63, d = (s >> 6) + 1;
    int i = t0 + il;
    if (i + d < SLEN) {
      double p = gs[il * GDIM + lane] * gs[(il + d) * GDIM + lane];
      for (int o = 32; o >= 1; o >>= 1) p += __shfl_xor(p, o, 64);
      if (lane == 0) simsT[((size_t)(b * SLEN + i)) * 16 + d] = p;
    }
  }
}

// K2b: per-token PRIORITY LIST as i8 partner-deltas, wave-per-token rank sort —
// no thread-local arrays (nothing can spill). Lane e<30 owns pair (d=(e>>1)+1,
// side=e&1); rank = #strictly-higher under (key desc, code asc) via 30 __shfl
// broadcasts; scatter delta->slot[rank] through per-wave LDS (same-wave program
// order). Empty slots = 0.
__global__ __launch_bounds__(256) void k_lists(const double* __restrict__ simsT,
                                               signed char* __restrict__ lists8) {
  __shared__ signed char stage[4][32];
  int wave = threadIdx.x >> 6, lane = threadIdx.x & 63;
  int t = blockIdx.x * 4 + wave;               // 0..NTOK-1
  int b = t >> 12, tt = t & (SLEN - 1);
  const double* sb = simsT + (size_t)b * SLEN * 16;
  int d = (lane >> 1) + 1;
  int side = lane & 1;
  bool valid = (lane < 30) && (side == 0 ? (tt + d < SLEN) : (tt - d >= 0));
  unsigned long long key = 0ULL;
  unsigned int code = 0xFFFFu;
  signed char delta = 0;
  if (valid) {
    int i = (side == 0) ? tt : (tt - d);
    double s = sb[(size_t)i * 16 + d];
    unsigned long long bits = (unsigned long long)__double_as_longlong(s);
    key = (bits & 0x8000000000000000ULL) ? ~bits : (bits | 0x8000000000000000ULL);
    code = (unsigned int)((i << 4) | d);
    delta = (side == 0) ? (signed char)d : (signed char)(-d);
  }
  int rank = 0;
#pragma clang loop unroll(disable)
  for (int q = 0; q < 30; ++q) {
    unsigned long long kq = __shfl(key, q, 64);
    unsigned int cq = __shfl(code, q, 64);
    if (kq != 0ULL && (kq > key || (kq == key && cq < code))) rank++;
  }
  if (lane < 32) stage[wave][lane] = 0;
  if (valid) stage[wave][rank] = delta;        // after init in program order
  if (lane < 32) lists8[(size_t)t * 32 + lane] = stage[wave][lane];
}

// K3a: SINGLE-WAVE PEEL, one 64-lane wave per batch. Lockstep wave => phase
// ordering is cheap (1-wave barriers); each lane owns 64 contiguous tokens and
// scans its bp-block as 8 u64 LDS reads with a w8==0 fast-skip (late rounds are
// nearly free). Invariant: bp[t]!=0 => t alive (maintenance zeroes dead bp), so
// the take phase needs no used[] reads. Mutual-best takes are disjoint => no
// races. Decision sequence identical to prior rounds (same lists, same rule).
__global__ __launch_bounds__(64) void k_peel(const signed char* __restrict__ lists8,
                                             unsigned short* __restrict__ tcodeG,
                                             int* __restrict__ tcntG) {
  int b = blockIdx.x;
  const signed char* lb = lists8 + (size_t)b * SLEN * 32;
  __shared__ signed char l8[SLEN * LDSL];     // 64 KB
  __shared__ signed char bp[SLEN];
  __shared__ unsigned char usedA[SLEN];
  __shared__ unsigned char cur[SLEN];
  __shared__ unsigned short takenCode[2048];
  __shared__ int takenCnt, baseCnt;
  int lane = threadIdx.x;
#pragma clang loop unroll(disable)
  for (int t = lane; t < SLEN; t += 64) {
    const unsigned long long* lp = (const unsigned long long*)(lb + (size_t)t * 32);
    unsigned long long v0 = lp[0], v1 = lp[1];
    unsigned long long* dp = (unsigned long long*)(l8 + t * LDSL);
    dp[0] = v0; dp[1] = v1;
    bp[t] = (signed char)(v0 & 0xFF);
    usedA[t] = 0; cur[t] = 0;
  }
  if (lane == 0) takenCnt = 0;
  __syncthreads();

  int tb = lane * 64;          // own contiguous 64-token block
#pragma clang loop unroll(disable)
  for (int round = 0; round < PEEL_ROUNDS; ++round) {
    if (lane == 0) baseCnt = takenCnt;
    __syncthreads();
    // take phase: bp snapshot per 8 tokens; no used[] reads (bp!=0 => alive)
#pragma clang loop unroll(disable)
    for (int c8 = 0; c8 < 8; ++c8) {
      unsigned long long w8 = *(const unsigned long long*)(bp + tb + c8 * 8);
      if (w8 == 0ULL) continue;
#pragma clang loop unroll(disable)
      for (int u = 0; u < 8; ++u) {
        signed char dlt = (signed char)(w8 >> (8 * u));
        if (dlt > 0) {
          int t = tb + c8 * 8 + u;
          int j = t + dlt;
          if (bp[j] == (signed char)(-dlt)) {
            int idx = atomicAdd(&takenCnt, 1);
            if (idx < 2048) takenCode[idx] = (unsigned short)((t << 4) | dlt);
            usedA[t] = 1; usedA[j] = 1;
          }
        }
      }
    }
    __syncthreads();
    int newCnt = takenCnt;
    if (newCnt == baseCnt) break;
    // maintenance: dead tokens -> bp=0; alive tokens advance cursor past dead partners
#pragma clang loop unroll(disable)
    for (int c8 = 0; c8 < 8; ++c8) {
      unsigned long long w8 = *(const unsigned long long*)(bp + tb + c8 * 8);
      if (w8 == 0ULL) continue;
#pragma clang loop unroll(disable)
      for (int u = 0; u < 8; ++u) {
        signed char dlt = (signed char)(w8 >> (8 * u));
        if (dlt == 0) continue;
        int t = tb + c8 * 8 + u;
        if (usedA[t]) { bp[t] = 0; continue; }
        int p = t + dlt;
        int cc = cur[t];
        bool adv = false;
#pragma clang loop unroll(disable)
        while (dlt != 0 && usedA[p]) {
          ++cc; adv = true;
          dlt = (cc < LDSL) ? l8[t * LDSL + cc]
              : ((cc < 32) ? lb[(size_t)t * 32 + cc] : (signed char)0);
          p = t + dlt;
        }
        if (adv) { cur[t] = (unsigned char)cc; bp[t] = dlt; }
      }
    }
    __syncthreads();
  }

  int m = min(takenCnt, 2048);
#pragma clang loop unroll(disable)
  for (int k = lane; k < m; k += 64) tcodeG[b * 2048 + k] = takenCode[k];
  if (lane == 0) tcntG[b] = m;
}

// K3b: top-r selection via MSD radix select on sortable-u64 f64 keys with
// small-straddle early exit -> exact full-key rank (key desc, code asc).
// Then prefix-sum compaction + per-row metadata + pos output.
__global__ __launch_bounds__(1024) void k_rank(const double* __restrict__ simsT_all,
                                               const unsigned short* __restrict__ tcodeG,
                                               const int* __restrict__ tcntG,
                                               const float* __restrict__ norms,
                                               int* __restrict__ kt, int* __restrict__ pjr,
                                               float* __restrict__ wir, float* __restrict__ wjr,
                                               float* __restrict__ out_pos) {
  int b = blockIdx.x;
  const double* simsT = simsT_all + (size_t)b * SLEN * 16;
  __shared__ unsigned long long key[2048];
  __shared__ unsigned short codeA[2048];
  __shared__ unsigned char state[2048];     // 0 = candidate, 1 = accepted, 2 = rejected
  __shared__ unsigned int hist[256];
  __shared__ unsigned int bcum[256];
  __shared__ unsigned int wsum[4];
  __shared__ int sharedB, sharedNeed, sdone, allAccept, smallStraddle;
  __shared__ unsigned short memberIdx[2048];
  __shared__ int memberCnt;
  __shared__ unsigned char meta[SLEN];      // 0=keep plain; 1..15=merge-right-d; 0x80=skip
  __shared__ int wTot[16], wOff[16];
  int tid = threadIdx.x;
  int m = min(tcntG[b], 2048);
#pragma clang loop unroll(disable)
  for (int t = tid; t < SLEN; t += 1024) meta[t] = 0;
#pragma clang loop unroll(disable)
  for (int k = tid; k < m; k += 1024) {
    unsigned short c = tcodeG[b * 2048 + k];
    codeA[k] = c;
    state[k] = 0;
    double s = simsT[(size_t)(c >> 4) * 16 + (c & 15)];
    unsigned long long bits = (unsigned long long)__double_as_longlong(s);
    key[k] = (bits & 0x8000000000000000ULL) ? ~bits : (bits | 0x8000000000000000ULL);
  }
  if (tid == 0) { sharedNeed = RSEL; sdone = 0; allAccept = (m <= RSEL); smallStraddle = 0; memberCnt = 0; }
  __syncthreads();

  if (!allAccept) {
#pragma clang loop unroll(disable)
    for (int pass = 0; pass < 8; ++pass) {
      if (tid < 256) hist[tid] = 0;
      __syncthreads();
      int sh = 56 - 8 * pass;
#pragma clang loop unroll(disable)
      for (int k = tid; k < m; k += 1024)
        if (!state[k]) atomicAdd(&hist[(unsigned int)(key[k] >> sh) & 0xFFu], 1u);
      __syncthreads();
      unsigned int v = 0, inc = 0;
      int lane = tid & 63, w = tid >> 6;
      if (tid < 256) {
        v = hist[255 - tid];
        inc = v;
        for (int o = 1; o < 64; o <<= 1) { unsigned int n = __shfl_up(inc, o, 64); if (lane >= o) inc += n; }
        if (lane == 63) wsum[w] = inc;
      }
      __syncthreads();
      if (tid < 256) {
        unsigned int off = 0;
        for (int ww = 0; ww < w; ++ww) off += wsum[ww];
        unsigned int incl = inc + off;
        bcum[255 - tid] = incl - v;
      }
      __syncthreads();
      if (tid < 256) {
        int bkt = 255 - tid;
        unsigned int ag = bcum[bkt];
        unsigned int need = (unsigned int)sharedNeed;
        if (ag < need && ag + hist[bkt] >= need) sharedB = bkt;
      }
      __syncthreads();
      int B = sharedB;
      unsigned int needInB = (unsigned int)sharedNeed - bcum[B];
#pragma clang loop unroll(disable)
      for (int k = tid; k < m; k += 1024) {
        if (!state[k]) {
          unsigned int bv = (unsigned int)(key[k] >> sh) & 0xFFu;
          if ((int)bv > B) state[k] = 1;
          else if ((int)bv < B) state[k] = 2;
        }
      }
      __syncthreads();
      if (tid == 0) {
        sharedNeed = (int)needInB;
        if (hist[B] == needInB) sdone = 1;
        else if (hist[B] <= 128) smallStraddle = 1;
      }
      __syncthreads();
      if (sdone || smallStraddle) break;
    }
  }
  __syncthreads();

  if (allAccept || sdone) {
#pragma clang loop unroll(disable)
    for (int k = tid; k < m; k += 1024) if (!state[k]) state[k] = 1;
  } else {
    // exact rank among remaining candidates by FULL key (desc), code (asc)
#pragma clang loop unroll(disable)
    for (int k = tid; k < m; k += 1024)
      if (!state[k]) { int idx = atomicAdd(&memberCnt, 1); memberIdx[idx] = (unsigned short)k; }
    __syncthreads();
    int mc = memberCnt;
    unsigned int need = (unsigned int)sharedNeed;
#pragma clang loop unroll(disable)
    for (int z = tid; z < mc; z += 1024) {
      int k = memberIdx[z];
      unsigned long long kk = key[k];
      unsigned short ck = codeA[k];
      unsigned int wr = 0;
#pragma clang loop unroll(disable)
      for (int q2 = 0; q2 < mc; ++q2) {
        int q = memberIdx[q2];
        unsigned long long kq = key[q];
        if (kq > kk || (kq == kk && codeA[q] < ck)) wr++;
      }
      if (wr < need) state[k] = 1;
    }
  }
  __syncthreads();
#pragma clang loop unroll(disable)
  for (int k = tid; k < m; k += 1024) {
    if (state[k] == 1) {
      unsigned short ck = codeA[k];
      int i = ck >> 4, d = ck & 15;
      meta[i] = (unsigned char)d;
      meta[i + d] = 0x80;
    }
  }
  __syncthreads();
  // compact kept tokens (prefix sum of !skip), 4 contiguous tokens per thread
  int cnt = 0; unsigned char kf[4];
  int tbase = tid * 4;
  for (int u = 0; u < 4; ++u) { kf[u] = (meta[tbase + u] & 0x80) ? 0 : 1; cnt += kf[u]; }
  int lane = tid & 63, wv = tid >> 6;
  int incl = cnt;
  for (int o = 1; o < 64; o <<= 1) { int n = __shfl_up(incl, o, 64); if (lane >= o) incl += n; }
  if (lane == 63) wTot[wv] = incl;
  __syncthreads();
  if (tid < 16) {
    int v2 = wTot[tid];
    for (int o = 1; o < 16; o <<= 1) { int n = __shfl_up(v2, o, 64); if (lane >= o) v2 += n; }
    wOff[tid] = v2 - wTot[tid];
  }
  __syncthreads();
  int pos = wOff[wv] + (incl - cnt);
  for (int u = 0; u < 4; ++u) {
    int t = tbase + u;
    if (kf[u]) {
      if (pos < KEEP) {
        int orow = b * KEEP + pos;
        kt[orow] = t;
        int d = meta[t] & 15;
        pjr[orow] = d ? (t + d) : -1;
        wir[orow] = norms[b * SLEN + t];
        wjr[orow] = d ? norms[b * SLEN + t + d] : 0.0f;
        out_pos[orow] = (float)(b * SLEN + t);
      }
      pos++;
    }
  }
}

// K4: fused gather — per output row: x row (512 f32, weighted merge) + source row
// (4096 f32, sum merge). Nontemporal loads/stores: all streams are touch-once.
// Indices clamped: poison can never fault.
__global__ __launch_bounds__(256) void k_gather(const float* __restrict__ x,
                                                const float* __restrict__ src,
                                                const int* __restrict__ kt, const int* __restrict__ pjr,
                                                const float* __restrict__ wir, const float* __restrict__ wjr,
                                                float* __restrict__ outx, float* __restrict__ outs) {
  int orow = blockIdx.x;
  int b = orow / KEEP;
  int t = kt[orow], pj = pjr[orow];
  int gi = min(max(b * SLEN + t, 0), NTOK - 1);
  int gj = min(b * SLEN + min(max(pj, 0), SLEN - 1), NTOK - 1);
  int c = threadIdx.x;
  // x part (threads 0..127)
  if (c < 128) {
    const f32x4* xi = (const f32x4*)(x + (size_t)gi * DDIM);
    f32x4 v = __builtin_nontemporal_load(&xi[c]);
    if (pj >= 0) {
      const f32x4* xj = (const f32x4*)(x + (size_t)gj * DDIM);
      f32x4 u = __builtin_nontemporal_load(&xj[c]);
      float wi = wir[orow], wj = wjr[orow];
      float inv = 1.0f / (wi + wj + 1e-8f);
      v = (v * wi + u * wj) * inv;
    }
    __builtin_nontemporal_store(v, (f32x4*)(outx + (size_t)orow * DDIM) + c);
  }
  // source part (all 256 threads, 4 f32x4 each)
  const f32x4* si = (const f32x4*)(src + (size_t)gi * NORIG);
  f32x4* o = (f32x4*)(outs + (size_t)orow * NORIG);
  if (pj >= 0) {
    const f32x4* sj = (const f32x4*)(src + (size_t)gj * NORIG);
    for (int u = 0; u < 4; ++u) {
      int c2 = c + u * 256;
      f32x4 a = __builtin_nontemporal_load(&si[c2]);
      f32x4 bb = __builtin_nontemporal_load(&sj[c2]);
      __builtin_nontemporal_store(a + bb, &o[c2]);
    }
  } else {
    for (int u = 0; u < 4; ++u) {
      int c2 = c + u * 256;
      f32x4 a = __builtin_nontemporal_load(&si[c2]);
      __builtin_nontemporal_store(a, &o[c2]);
    }
  }
}

extern "C" void kernel_launch(void* const* d_in, const int* in_sizes, int n_in,
                              void* d_out, int out_size, void* d_ws, size_t ws_size,
                              hipStream_t stream) {
  if (ws_size < WS_NEEDED) return;  // fail fast & clean instead of faulting

  const float* x = (const float*)d_in[0];
  const float* source = (const float*)d_in[1];
  // d_in[2] = position_ids (== arange(B*S)); d_in[3] = r (1024); d_in[4] = window_size (16)
  const float* Wm = (const float*)d_in[5];

  char* ws = (char*)d_ws;
  double* gn = (double*)(ws + OFF_GN);
  double* simsT = (double*)(ws + OFF_SIMST);
  float* norms = (float*)(ws + OFF_NORMS);
  unsigned short* tcode = (unsigned short*)(ws + OFF_TCODE);  // reuses gn (dead after k_sims)
  int* tcnt = (int*)(ws + OFF_TCNT);
  signed char* lists8 = (signed char*)(ws + OFF_LISTS);       // reuses gn (dead after k_sims)
  int* kt = (int*)(ws + OFF_KT);
  int* pjr = (int*)(ws + OFF_PJR);
  float* wir = (float*)(ws + OFF_WIR);
  float* wjr = (float*)(ws + OFF_WJR);

  float* out = (float*)d_out;
  float* outx = out + OUTX_OFF;
  float* outs = out + OUTS_OFF;
  float* outp = out + OUTP_OFF;

  k_proj<<<(BATCH * SLEN) / 16, 256, 0, stream>>>(x, Wm, gn, norms);
  k_sims<<<BATCH * (SLEN / 64), 256, 0, stream>>>(gn, simsT);
  k_lists<<<NTOK / 4, 256, 0, stream>>>(simsT, lists8);
  k_peel<<<BATCH, 64, 0, stream>>>(lists8, tcode, tcnt);
  k_rank<<<BATCH, 1024, 0, stream>>>(simsT, tcode, tcnt, norms, kt, pjr, wir, wjr, outp);
  k_gather<<<BATCH * KEEP, 256, 0, stream>>>(x, source, kt, pjr, wir, wjr, outx, outs);
}

// Round 17
// 331.275 us; speedup vs baseline: 2.6857x; 2.6857x over previous
//
#include <hip/hip_runtime.h>

#define BATCH 4
#define SLEN 4096
#define DDIM 512
#define GDIM 64
#define NORIG 4096
#define WMAX 15            // d = 1..15 (window_size 16)
#define RSEL 1024
#define KEEP (SLEN - RSEL) // 3072
#define NTOK (BATCH * SLEN)
#define PEEL_ROUNDS 256
#define LDSL 32            // full 32-entry list LDS-resident (no global fallback)

typedef float __attribute__((ext_vector_type(4))) f32x4;

// ---- workspace layout (bytes) ----
// gn region [0, 8.4MB) is dead after k_sims -> reuse for delta lists.
#define OFF_LISTS ((size_t)0)            // i8     [B][S][32]   = 524,288  (reuses gn)
#define OFF_GN    ((size_t)0)            // double [B][S][G]    = 8,388,608
#define OFF_SIMST ((size_t)8388608)      // double [B][S][16]   = 2,097,152  (slot d=1..15)
#define OFF_NORMS ((size_t)10485760)     // float  [B][S]       = 65,536
#define OFF_KT    ((size_t)10584064)     // int    [B][KEEP]    = 49,152
#define OFF_PJR   ((size_t)10633216)     // int    [B][KEEP]
#define OFF_WIR   ((size_t)10682368)     // float  [B][KEEP]
#define OFF_WJR   ((size_t)10731520)     // float  [B][KEEP]
#define WS_NEEDED ((size_t)10780672)

// ---- output layout (f32 elements) ----
#define OUTX_OFF 0
#define OUTS_OFF 6291456          // 4*3072*512
#define OUTP_OFF 56623104         // + 4*3072*4096

// K1: g = x@W in f64, norms, gn = g/max(norm,1e-12).
__global__ __launch_bounds__(256) void k_proj(const float* __restrict__ x,
                                              const float* __restrict__ Wm,
                                              double* __restrict__ gn,
                                              float* __restrict__ norms) {
  __shared__ float xs[16 * DDIM];
  int base = blockIdx.x * 16;
  const float4* src = (const float4*)(x + (size_t)base * DDIM);
  float4* dstv = (float4*)xs;
  for (int idx = threadIdx.x; idx < 16 * DDIM / 4; idx += 256) dstv[idx] = src[idx];
  __syncthreads();
  int lane = threadIdx.x & 63;
  int wv = threadIdx.x >> 6;
  double acc0 = 0, acc1 = 0, acc2 = 0, acc3 = 0;
  const float* xw = xs + wv * 4 * DDIM;
  for (int d = 0; d < DDIM; ++d) {
    double wval = (double)Wm[d * GDIM + lane];
    acc0 += (double)xw[d] * wval;
    acc1 += (double)xw[DDIM + d] * wval;
    acc2 += (double)xw[2 * DDIM + d] * wval;
    acc3 += (double)xw[3 * DDIM + d] * wval;
  }
  double accs[4] = {acc0, acc1, acc2, acc3};
  for (int k = 0; k < 4; ++k) {
    double a = accs[k];
    double ss = a * a;
    for (int o = 32; o >= 1; o >>= 1) ss += __shfl_xor(ss, o, 64);
    double nrm = sqrt(ss);
    int tok = base + wv * 4 + k;
    if (lane == 0) norms[tok] = (float)nrm;
    double denom = nrm > 1e-12 ? nrm : 1e-12;
    gn[(size_t)tok * GDIM + lane] = a / denom;
  }
}

// K2: sims for pairs (i, i+d), token-major: simsT[(b*S+i)*16 + d].
__global__ __launch_bounds__(256) void k_sims(const double* __restrict__ gn,
                                              double* __restrict__ simsT) {
  int blk = blockIdx.x;
  int b = blk >> 6;
  int t0 = (blk & 63) * 64;
  int nrows = min(64 + WMAX, SLEN - t0);
  __shared__ double gs[(64 + WMAX) * GDIM];
  const double* src = gn + ((size_t)b * SLEN + t0) * GDIM;
  for (int idx = threadIdx.x; idx < nrows * GDIM; idx += 256) gs[idx] = src[idx];
  __syncthreads();
  int lane = threadIdx.x & 63, wv = threadIdx.x >> 6;
  for (int s = wv; s < 64 * WMAX; s += 4) {
    int il = s & 63, d = (s >> 6) + 1;
    int i = t0 + il;
    if (i + d < SLEN) {
      double p = gs[il * GDIM + lane] * gs[(il + d) * GDIM + lane];
      for (int o = 32; o >= 1; o >>= 1) p += __shfl_xor(p, o, 64);
      if (lane == 0) simsT[((size_t)(b * SLEN + i)) * 16 + d] = p;
    }
  }
}

// K2b: per-token PRIORITY LIST as i8 partner-deltas, wave-per-token rank sort —
// no thread-local arrays (nothing can spill). Lane e<30 owns pair (d=(e>>1)+1,
// side=e&1); rank = #strictly-higher under (key desc, code asc) via 30 __shfl
// broadcasts; scatter delta->slot[rank] through per-wave LDS (same-wave program
// order). Empty slots = 0.
__global__ __launch_bounds__(256) void k_lists(const double* __restrict__ simsT,
                                               signed char* __restrict__ lists8) {
  __shared__ signed char stage[4][32];
  int wave = threadIdx.x >> 6, lane = threadIdx.x & 63;
  int t = blockIdx.x * 4 + wave;               // 0..NTOK-1
  int b = t >> 12, tt = t & (SLEN - 1);
  const double* sb = simsT + (size_t)b * SLEN * 16;
  int d = (lane >> 1) + 1;
  int side = lane & 1;
  bool valid = (lane < 30) && (side == 0 ? (tt + d < SLEN) : (tt - d >= 0));
  unsigned long long key = 0ULL;
  unsigned int code = 0xFFFFu;
  signed char delta = 0;
  if (valid) {
    int i = (side == 0) ? tt : (tt - d);
    double s = sb[(size_t)i * 16 + d];
    unsigned long long bits = (unsigned long long)__double_as_longlong(s);
    key = (bits & 0x8000000000000000ULL) ? ~bits : (bits | 0x8000000000000000ULL);
    code = (unsigned int)((i << 4) | d);
    delta = (side == 0) ? (signed char)d : (signed char)(-d);
  }
  int rank = 0;
#pragma clang loop unroll(disable)
  for (int q = 0; q < 30; ++q) {
    unsigned long long kq = __shfl(key, q, 64);
    unsigned int cq = __shfl(code, q, 64);
    if (kq != 0ULL && (kq > key || (kq == key && cq < code))) rank++;
  }
  if (lane < 32) stage[wave][lane] = 0;
  if (valid) stage[wave][rank] = delta;        // after init in program order
  if (lane < 32) lists8[(size_t)t * 32 + lane] = stage[wave][lane];
}

// K3: fused PEEL + RANK + compaction, one 1024-thread block per batch (the
// proven shape: wave-parallelism hides the LDS latency chains; 256-thr and
// 1-wave variants both regressed). Deltas vs the 346.9us build: LDSL=32 (whole
// list LDS-resident, no global fallback on the walk) and u32 bp-snapshots with
// zero-skip over 4 contiguous tokens/thread. Decision sequence is identical:
// mutual-best peel == sequential greedy under (sim desc, i asc, d asc);
// bp!=0 => alive (maintenance zeroes dead bp; mutual-best pairs are disjoint).
__global__ __launch_bounds__(1024) void k_match(const signed char* __restrict__ lists8,
                                                const double* __restrict__ simsT_all,
                                                const float* __restrict__ norms,
                                                int* __restrict__ kt, int* __restrict__ pjr,
                                                float* __restrict__ wir, float* __restrict__ wjr,
                                                float* __restrict__ out_pos) {
  int b = blockIdx.x;
  const signed char* lb = lists8 + (size_t)b * SLEN * 32;
  const double* simsT = simsT_all + (size_t)b * SLEN * 16;
  __shared__ __align__(16) unsigned char big[SLEN * LDSL]; // peel: l8 / rank: overlay
  __shared__ __align__(8) signed char bp[SLEN];
  __shared__ unsigned char usedA[SLEN];
  __shared__ unsigned char cur[SLEN];
  __shared__ unsigned short takenCode[2048];
  __shared__ unsigned char meta[SLEN];        // 0=keep plain; 1..15=merge-right-d; 0x80=skip
  __shared__ int takenCnt, baseCnt;
  __shared__ int sharedB, sharedNeed, sdone, allAccept, smallStraddle;
  __shared__ int memberCnt;
  __shared__ int wTot[16], wOff[16];
  signed char* l8 = (signed char*)big;
  int tid = threadIdx.x;

  // stage full 32-entry lists (4 u64 per token, coalesced), init state
#pragma clang loop unroll(disable)
  for (int t = tid; t < SLEN; t += 1024) {
    const unsigned long long* lp = (const unsigned long long*)(lb + (size_t)t * 32);
    unsigned long long v0 = lp[0], v1 = lp[1], v2 = lp[2], v3 = lp[3];
    unsigned long long* dp = (unsigned long long*)(l8 + t * LDSL);
    dp[0] = v0; dp[1] = v1; dp[2] = v2; dp[3] = v3;
    bp[t] = (signed char)(v0 & 0xFF);
    usedA[t] = 0; cur[t] = 0; meta[t] = 0;
  }
  if (tid == 0) takenCnt = 0;
  __syncthreads();

  int tb4 = tid * 4;           // own 4 contiguous tokens
#pragma clang loop unroll(disable)
  for (int round = 0; round < PEEL_ROUNDS; ++round) {
    if (tid == 0) baseCnt = takenCnt;
    __syncthreads();
    // take phase: u32 snapshot + zero-skip; bp!=0 => alive, no used[] reads
    {
      unsigned int w4 = *(const unsigned int*)(bp + tb4);
      if (w4 != 0u) {
#pragma clang loop unroll(disable)
        for (int u = 0; u < 4; ++u) {
          signed char dlt = (signed char)(w4 >> (8 * u));
          if (dlt > 0) {
            int t = tb4 + u;
            int j = t + dlt;
            if (bp[j] == (signed char)(-dlt)) {
              int idx = atomicAdd(&takenCnt, 1);
              if (idx < 2048) takenCode[idx] = (unsigned short)((t << 4) | dlt);
              usedA[t] = 1; usedA[j] = 1;
            }
          }
        }
      }
    }
    __syncthreads();
    int newCnt = takenCnt;
    if (newCnt == baseCnt) break;
    // maintenance: dead -> bp=0; alive advance cursor past dead partners (pure LDS)
    {
      unsigned int w4 = *(const unsigned int*)(bp + tb4);
      if (w4 != 0u) {
#pragma clang loop unroll(disable)
        for (int u = 0; u < 4; ++u) {
          signed char dlt = (signed char)(w4 >> (8 * u));
          if (dlt == 0) continue;
          int t = tb4 + u;
          if (usedA[t]) { bp[t] = 0; continue; }
          int p = t + dlt;
          int cc = cur[t];
          bool adv = false;
#pragma clang loop unroll(disable)
          while (dlt != 0 && usedA[p]) {
            ++cc; adv = true;
            dlt = (cc < LDSL) ? l8[t * LDSL + cc] : (signed char)0;
            p = t + dlt;
          }
          if (adv) { cur[t] = (unsigned char)cc; bp[t] = dlt; }
        }
      }
    }
    __syncthreads();
  }

  // ---- RANK phase: overlay rank arrays onto big (list LDS is dead) ----
  unsigned long long* key = (unsigned long long*)big;            // 16384 B
  unsigned short* codeA = (unsigned short*)(big + 16384);        // 4096 B
  unsigned char* state = (unsigned char*)(big + 20480);          // 2048 B
  unsigned int* hist = (unsigned int*)(big + 22528);             // 1024 B
  unsigned int* bcum = (unsigned int*)(big + 23552);             // 1024 B
  unsigned int* wsum = (unsigned int*)(big + 24576);             // 16 B
  unsigned short* memberIdx = (unsigned short*)(big + 24704);    // 4096 B
  int m = min(takenCnt, 2048);
  __syncthreads();   // all peel reads of big done before overlay writes
#pragma clang loop unroll(disable)
  for (int k = tid; k < m; k += 1024) {
    unsigned short c = takenCode[k];
    codeA[k] = c;
    state[k] = 0;
    double s = simsT[(size_t)(c >> 4) * 16 + (c & 15)];
    unsigned long long bits = (unsigned long long)__double_as_longlong(s);
    key[k] = (bits & 0x8000000000000000ULL) ? ~bits : (bits | 0x8000000000000000ULL);
  }
  if (tid == 0) { sharedNeed = RSEL; sdone = 0; allAccept = (m <= RSEL); smallStraddle = 0; memberCnt = 0; }
  __syncthreads();

  if (!allAccept) {
#pragma clang loop unroll(disable)
    for (int pass = 0; pass < 8; ++pass) {
      if (tid < 256) hist[tid] = 0;
      __syncthreads();
      int sh = 56 - 8 * pass;
#pragma clang loop unroll(disable)
      for (int k = tid; k < m; k += 1024)
        if (!state[k]) atomicAdd(&hist[(unsigned int)(key[k] >> sh) & 0xFFu], 1u);
      __syncthreads();
      unsigned int v = 0, inc = 0;
      int lane = tid & 63, w = tid >> 6;
      if (tid < 256) {
        v = hist[255 - tid];
        inc = v;
        for (int o = 1; o < 64; o <<= 1) { unsigned int n = __shfl_up(inc, o, 64); if (lane >= o) inc += n; }
        if (lane == 63) wsum[w] = inc;
      }
      __syncthreads();
      if (tid < 256) {
        unsigned int off = 0;
        for (int ww = 0; ww < w; ++ww) off += wsum[ww];
        unsigned int incl = inc + off;
        bcum[255 - tid] = incl - v;
      }
      __syncthreads();
      if (tid < 256) {
        int bkt = 255 - tid;
        unsigned int ag = bcum[bkt];
        unsigned int need = (unsigned int)sharedNeed;
        if (ag < need && ag + hist[bkt] >= need) sharedB = bkt;
      }
      __syncthreads();
      int B = sharedB;
      unsigned int needInB = (unsigned int)sharedNeed - bcum[B];
#pragma clang loop unroll(disable)
      for (int k = tid; k < m; k += 1024) {
        if (!state[k]) {
          unsigned int bv = (unsigned int)(key[k] >> sh) & 0xFFu;
          if ((int)bv > B) state[k] = 1;
          else if ((int)bv < B) state[k] = 2;
        }
      }
      __syncthreads();
      if (tid == 0) {
        sharedNeed = (int)needInB;
        if (hist[B] == needInB) sdone = 1;
        else if (hist[B] <= 128) smallStraddle = 1;   // few members: exact rank is cheap
      }
      __syncthreads();
      if (sdone || smallStraddle) break;
    }
  }
  __syncthreads();

  if (allAccept || sdone) {
#pragma clang loop unroll(disable)
    for (int k = tid; k < m; k += 1024) if (!state[k]) state[k] = 1;
  } else {
    // exact rank among remaining candidates by FULL key (desc), code (asc) —
    // correct mid-radix (members share only the processed prefix) and post-radix.
#pragma clang loop unroll(disable)
    for (int k = tid; k < m; k += 1024)
      if (!state[k]) { int idx = atomicAdd(&memberCnt, 1); memberIdx[idx] = (unsigned short)k; }
    __syncthreads();
    int mc = memberCnt;
    unsigned int need = (unsigned int)sharedNeed;
#pragma clang loop unroll(disable)
    for (int z = tid; z < mc; z += 1024) {
      int k = memberIdx[z];
      unsigned long long kk = key[k];
      unsigned short ck = codeA[k];
      unsigned int wr = 0;
#pragma clang loop unroll(disable)
      for (int q2 = 0; q2 < mc; ++q2) {
        int q = memberIdx[q2];
        unsigned long long kq = key[q];
        if (kq > kk || (kq == kk && codeA[q] < ck)) wr++;
      }
      if (wr < need) state[k] = 1;
    }
  }
  __syncthreads();
#pragma clang loop unroll(disable)
  for (int k = tid; k < m; k += 1024) {
    if (state[k] == 1) {
      unsigned short ck = codeA[k];
      int i = ck >> 4, d = ck & 15;
      meta[i] = (unsigned char)d;
      meta[i + d] = 0x80;
    }
  }
  __syncthreads();
  // compact kept tokens (prefix sum of !skip), 4 contiguous tokens per thread
  int cnt = 0; unsigned char kf[4];
  int tbase = tid * 4;
  for (int u = 0; u < 4; ++u) { kf[u] = (meta[tbase + u] & 0x80) ? 0 : 1; cnt += kf[u]; }
  int lane = tid & 63, wv = tid >> 6;
  int incl = cnt;
  for (int o = 1; o < 64; o <<= 1) { int n = __shfl_up(incl, o, 64); if (lane >= o) incl += n; }
  if (lane == 63) wTot[wv] = incl;
  __syncthreads();
  if (tid < 16) {
    int v2 = wTot[tid];
    for (int o = 1; o < 16; o <<= 1) { int n = __shfl_up(v2, o, 64); if (lane >= o) v2 += n; }
    wOff[tid] = v2 - wTot[tid];
  }
  __syncthreads();
  int pos = wOff[wv] + (incl - cnt);
  for (int u = 0; u < 4; ++u) {
    int t = tbase + u;
    if (kf[u]) {
      if (pos < KEEP) {
        int orow = b * KEEP + pos;
        kt[orow] = t;
        int d = meta[t] & 15;
        pjr[orow] = d ? (t + d) : -1;
        wir[orow] = norms[b * SLEN + t];
        wjr[orow] = d ? norms[b * SLEN + t + d] : 0.0f;
        out_pos[orow] = (float)(b * SLEN + t);
      }
      pos++;
    }
  }
}

// K4: fused gather — per output row: x row (512 f32, weighted merge) + source row
// (4096 f32, sum merge). Nontemporal loads/stores: all streams are touch-once.
// Indices clamped: poison can never fault.
__global__ __launch_bounds__(256) void k_gather(const float* __restrict__ x,
                                                const float* __restrict__ src,
                                                const int* __restrict__ kt, const int* __restrict__ pjr,
                                                const float* __restrict__ wir, const float* __restrict__ wjr,
                                                float* __restrict__ outx, float* __restrict__ outs) {
  int orow = blockIdx.x;
  int b = orow / KEEP;
  int t = kt[orow], pj = pjr[orow];
  int gi = min(max(b * SLEN + t, 0), NTOK - 1);
  int gj = min(b * SLEN + min(max(pj, 0), SLEN - 1), NTOK - 1);
  int c = threadIdx.x;
  // x part (threads 0..127)
  if (c < 128) {
    const f32x4* xi = (const f32x4*)(x + (size_t)gi * DDIM);
    f32x4 v = __builtin_nontemporal_load(&xi[c]);
    if (pj >= 0) {
      const f32x4* xj = (const f32x4*)(x + (size_t)gj * DDIM);
      f32x4 u = __builtin_nontemporal_load(&xj[c]);
      float wi = wir[orow], wj = wjr[orow];
      float inv = 1.0f / (wi + wj + 1e-8f);
      v = (v * wi + u * wj) * inv;
    }
    __builtin_nontemporal_store(v, (f32x4*)(outx + (size_t)orow * DDIM) + c);
  }
  // source part (all 256 threads, 4 f32x4 each)
  const f32x4* si = (const f32x4*)(src + (size_t)gi * NORIG);
  f32x4* o = (f32x4*)(outs + (size_t)orow * NORIG);
  if (pj >= 0) {
    const f32x4* sj = (const f32x4*)(src + (size_t)gj * NORIG);
    for (int u = 0; u < 4; ++u) {
      int c2 = c + u * 256;
      f32x4 a = __builtin_nontemporal_load(&si[c2]);
      f32x4 bb = __builtin_nontemporal_load(&sj[c2]);
      __builtin_nontemporal_store(a + bb, &o[c2]);
    }
  } else {
    for (int u = 0; u < 4; ++u) {
      int c2 = c + u * 256;
      f32x4 a = __builtin_nontemporal_load(&si[c2]);
      __builtin_nontemporal_store(a, &o[c2]);
    }
  }
}

extern "C" void kernel_launch(void* const* d_in, const int* in_sizes, int n_in,
                              void* d_out, int out_size, void* d_ws, size_t ws_size,
                              hipStream_t stream) {
  if (ws_size < WS_NEEDED) return;  // fail fast & clean instead of faulting

  const float* x = (const float*)d_in[0];
  const float* source = (const float*)d_in[1];
  // d_in[2] = position_ids (== arange(B*S)); d_in[3] = r (1024); d_in[4] = window_size (16)
  const float* Wm = (const float*)d_in[5];

  char* ws = (char*)d_ws;
  double* gn = (double*)(ws + OFF_GN);
  double* simsT = (double*)(ws + OFF_SIMST);
  float* norms = (float*)(ws + OFF_NORMS);
  signed char* lists8 = (signed char*)(ws + OFF_LISTS);   // reuses gn (dead after k_sims)
  int* kt = (int*)(ws + OFF_KT);
  int* pjr = (int*)(ws + OFF_PJR);
  float* wir = (float*)(ws + OFF_WIR);
  float* wjr = (float*)(ws + OFF_WJR);

  float* out = (float*)d_out;
  float* outx = out + OUTX_OFF;
  float* outs = out + OUTS_OFF;
  float* outp = out + OUTP_OFF;

  k_proj<<<(BATCH * SLEN) / 16, 256, 0, stream>>>(x, Wm, gn, norms);
  k_sims<<<BATCH * (SLEN / 64), 256, 0, stream>>>(gn, simsT);
  k_lists<<<NTOK / 4, 256, 0, stream>>>(simsT, lists8);
  k_match<<<BATCH, 1024, 0, stream>>>(lists8, simsT, norms, kt, pjr, wir, wjr, outp);
  k_gather<<<BATCH * KEEP, 256, 0, stream>>>(x, source, kt, pjr, wir, wjr, outx, outs);
}